// Round 4
// baseline (917.910 us; speedup 1.0000x reference)
//
#include <hip/hip_runtime.h>
#include <hip/hip_bf16.h>

// Problem constants (BayesianLinear): IN_F=64, OUT_F=32, N=2080, B*S=16384
#define IN_F  64
#define OUT_F 32
#define NV    2080           // N
#define NPAD  2176           // 17*128
#define MM    16384          // tokens
#define KK    2080           // contraction dim
#define NBN   17             // column tiles
#define BM    256            // row-tile

typedef __attribute__((ext_vector_type(4))) float f32x4;
typedef __bf16 bf16x8 __attribute__((ext_vector_type(8)));

using gas_ptr = const __attribute__((address_space(1))) void*;
using lds_ptr = __attribute__((address_space(3))) void*;

// ---------------------------------------------------------------------------
// Kernel 1: build L (bf16, row-major [NPAD][KK]); rows >= NV are zero.
// ---------------------------------------------------------------------------
__global__ __launch_bounds__(256) void build_L_k(const float* __restrict__ cov,
                                                 const float* __restrict__ logvar,
                                                 __hip_bfloat16* __restrict__ LB) {
    const int idx = blockIdx.x * 256 + threadIdx.x;   // over NPAD*KK
    const int m = idx / KK;
    const int k = idx - m * KK;
    float v = 0.0f;
    if (m < NV) {
        if (k < m)       v = cov[(size_t)(m * (m - 1) / 2) + k];
        else if (k == m) v = expf(0.5f * logvar[m]);
    }
    LB[idx] = __float2bfloat16(v);
}

// ---------------------------------------------------------------------------
// Kernel 2 (v5): BM=256 x 128 tile, Z-accumulated in AGPRs (contract once in
// the epilogue -- v4 showed per-step contraction is VALU-bound).
//   A (eps fp32): loaded DIRECTLY global->registers per fragment -- the LDS
//     round-trip is pointless for A since each lane's fragment is 8 contiguous
//     fp32 at row*KK + t*32 + quad*8 (the LDS swizzle cancels).  2 dwordx4 per
//     frag, 16 rows x 128B per instr (coalesced, L2-hot strip).  In-reg cvt to
//     bf16.  Ping-pong raA/raB, distance-1 prefetch issued pre-MFMA.
//   B (L bf16): glds triple-buffer distance-2 (unchanged, verified).
//   Counted vmcnt only: barrier wait = vmcnt(10) keeps A(t+1)[8]+B(t+2)[2] in
//     flight; cvt's A-wait is compiler-inserted (drains A(t)+B(t) exactly).
//     No lgkm drains in the loop, no ds_writes at all.
//   Per-iter LDS: 8 ds_read_b128 per wave (B frags only; was 12 + 4 writes).
//   LDS 28 KB -> 3+ blocks/CU co-resident.
//   Triangular: kblocks=min(65,4bn+4); tail frag-skip jlo=2t-8bn.
// ---------------------------------------------------------------------------
__global__ __launch_bounds__(256, 2) void gemm_v5_k(const float* __restrict__ A,
                                                    const __hip_bfloat16* __restrict__ BT,
                                                    const float* __restrict__ loc,
                                                    const float* __restrict__ x,
                                                    float* __restrict__ Ypart) {
    __shared__ __align__(16) __hip_bfloat16 Bs[3][128 * 32];   // 24 KB
    __shared__ float xs[BM][4];                                //  4 KB

    const int tid  = threadIdx.x;
    const int bm   = blockIdx.x;             // 0..63
    const int bn   = (NBN - 1) - blockIdx.y; // heaviest (bn=16) first
    const int wave = tid >> 6;
    const int lane = tid & 63;
    const int quad = lane >> 4;
    const int r16  = lane & 15;
    const int kblocks = min(KK / 32, 4 * bn + 4);   // >= 4 always

    // xs: weight for h = 4bn-1+c; bias (1.0) at bn==0,c==0.
    {
        const int row = bm * BM + tid;
#pragma unroll
        for (int c = 0; c < 4; c++) {
            const int h = 4 * bn - 1 + c;
            float w = 0.0f;
            if (bn == 0 && c == 0)       w = 1.0f;
            else if (h >= 0 && h < IN_F) w = x[(size_t)row * IN_F + h];
            xs[tid][c] = w;
        }
    }

    const float*          __restrict__ Ag = A  + (size_t)bm * BM * KK;   // fp32 eps
    const __hip_bfloat16* __restrict__ Bg = BT + (size_t)bn * 128 * KK;  // bf16 L

    // A fragment global offsets (fp32 elements): lane frag i = 8 consecutive
    // f32 at row_i*KK + quad*8, row_i = 64*wave + 16*i + r16.
    size_t arofs[4];
#pragma unroll
    for (int i = 0; i < 4; i++) {
        const int row = 64 * wave + 16 * i + r16;
        arofs[i] = (size_t)row * KK + (size_t)(quad * 8);
    }

    // B staging map: 512 chunks, 2/thread; chunk c -> slot (c>>2, c&3) holding
    // global part p=(c&3)^((row>>1)&3)  (verified glds swizzle path).
    size_t bgofs[2]; int bldso[2];
#pragma unroll
    for (int u = 0; u < 2; u++) {
        const int c = tid + 256 * u;
        const int r = c >> 2, p = (c & 3) ^ ((r >> 1) & 3);
        bgofs[u] = (size_t)r * KK + (size_t)(p * 8);
        bldso[u] = c * 8;
    }

    // B fragment-read LDS offsets (elements), verified swizzle
    int bofs[8];
#pragma unroll
    for (int j = 0; j < 8; j++) {
        const int brow = 16 * j + r16;
        bofs[j] = brow * 32 + (quad ^ ((brow >> 1) & 3)) * 8;
    }

    f32x4 acc[4][8];
#pragma unroll
    for (int i = 0; i < 4; i++)
#pragma unroll
        for (int j = 0; j < 8; j++) acc[i][j] = f32x4{0.f, 0.f, 0.f, 0.f};

    f32x4 raA[8], raB[8];   // ping-pong in-flight A fragments (fp32)

    auto loadA = [&](f32x4 (&r)[8], int t) __attribute__((always_inline)) {
        const float* p = Ag + (size_t)t * 32;
#pragma unroll
        for (int i = 0; i < 4; i++) {
            r[2 * i]     = *(const f32x4*)(p + arofs[i]);
            r[2 * i + 1] = *(const f32x4*)(p + arofs[i] + 4);
        }
    };
    auto stageB = [&](int t, int buf) __attribute__((always_inline)) {
        const __hip_bfloat16* bp = Bg + (size_t)t * 32;
#pragma unroll
        for (int u = 0; u < 2; u++)
            __builtin_amdgcn_global_load_lds((gas_ptr)(bp + bgofs[u]),
                                             (lds_ptr)(&Bs[buf][0] + bldso[u]), 16, 0, 0);
    };

    // --- prologue: B(0), A(0), B(1) in flight; barrier for xs only ---
    stageB(0, 0);
    loadA(raA, 0);
    stageB(1, 1);
    __builtin_amdgcn_sched_barrier(0);
    asm volatile("s_waitcnt lgkmcnt(0)" ::: "memory");   // xs committed
    __builtin_amdgcn_s_barrier();
    __builtin_amdgcn_sched_barrier(0);

    // steady-state issue order per iter t: loadA(t+1), stageB(t+2).
    // outstanding at cvt(A(t)): A(t)[8], B(t+1)[2], A(t+1)[8], B(t+2)[2];
    // compiler-inserted wait for cvt drains A(t) (and the older B(t)).
    // pre-barrier: vmcnt(10) drains B(t+1), keeps A(t+1)+B(t+2).
    auto iter = [&](int t, f32x4 (&cur)[8], f32x4 (&nxt)[8], int jlo)
        __attribute__((always_inline)) {
        const bool pfA = (t + 1 < kblocks);
        const bool pfB = (t + 2 < kblocks);
        if (pfA) loadA(nxt, t + 1);
        if (pfB) stageB(t + 2, (t + 2) % 3);
        __builtin_amdgcn_sched_barrier(0);

        bf16x8 af[4];                       // cvt waits A(t) here (auto vmcnt)
#pragma unroll
        for (int i = 0; i < 4; i++) {
#pragma unroll
            for (int q = 0; q < 4; q++) {
                af[i][q]     = (__bf16)cur[2 * i][q];
                af[i][4 + q] = (__bf16)cur[2 * i + 1][q];
            }
        }
        const __hip_bfloat16* bs = &Bs[t % 3][0];
        __builtin_amdgcn_s_setprio(1);
#pragma unroll
        for (int j = 0; j < 8; j++) {
            if (j >= jlo) {
                const bf16x8 bfr = *(const bf16x8*)(bs + bofs[j]);
#pragma unroll
                for (int i = 0; i < 4; i++)
                    acc[i][j] = __builtin_amdgcn_mfma_f32_16x16x32_bf16(af[i], bfr, acc[i][j], 0, 0, 0);
            }
        }
        __builtin_amdgcn_s_setprio(0);

        if (pfA) {
            if (pfB) { asm volatile("s_waitcnt vmcnt(10)" ::: "memory"); }
            else     { asm volatile("s_waitcnt vmcnt(8)"  ::: "memory"); }
            __builtin_amdgcn_s_barrier();
            __builtin_amdgcn_sched_barrier(0);
        }
    };

    const int t_full = min(kblocks, 4 * bn + 1);   // jlo==0 region
    int t = 0;
    for (; t + 1 < t_full; t += 2) {               // hot pair-loop, jlo=0
        iter(t,     raA, raB, 0);
        iter(t + 1, raB, raA, 0);
    }
    {   // remaining iters (<=4): runtime jlo, explicit parity
        bool useA = true;                          // t is even here -> cur=raA
        for (; t < kblocks; ++t, useA = !useA) {
            const int jl = (2 * t > 8 * bn) ? (2 * t - 8 * bn) : 0;
            if (useA) iter(t, raA, raB, jl);
            else      iter(t, raB, raA, jl);
        }
    }

    // in-lane epilogue.  C/D layout (m89): col=lane&15 (per 16-tile), row=quad*4+reg
    float locv[8];
#pragma unroll
    for (int j = 0; j < 8; j++) {
        const int col = bn * 128 + 16 * j + r16;
        locv[j] = (col < NV) ? loc[col] : 0.0f;
    }

    float* yp = Ypart + ((size_t)bn * MM + (size_t)bm * BM) * OUT_F;
#pragma unroll
    for (int i = 0; i < 4; i++) {
#pragma unroll
        for (int r = 0; r < 4; r++) {
            const int tl = 64 * wave + 16 * i + 4 * quad + r;
            float v0 = 0.0f, v1 = 0.0f;
#pragma unroll
            for (int c = 0; c < 4; c++) {
                const float w = xs[tl][c];
                v0 += w * (acc[i][2 * c][r]     + locv[2 * c]);
                v1 += w * (acc[i][2 * c + 1][r] + locv[2 * c + 1]);
            }
            yp[(size_t)tl * OUT_F + r16]      = v0;
            yp[(size_t)tl * OUT_F + 16 + r16] = v1;
        }
    }
}

// ---------------------------------------------------------------------------
// Kernel 3: reduce 17 partials -> y
// ---------------------------------------------------------------------------
__global__ __launch_bounds__(256) void reduce_y_k(const float4* __restrict__ yp,
                                                  float4* __restrict__ y) {
    const size_t i = (size_t)blockIdx.x * 256 + threadIdx.x;   // MM*32/4
    float4 s = yp[i];
#pragma unroll
    for (int b = 1; b < NBN; b++) {
        float4 v = yp[i + (size_t)b * (MM * OUT_F / 4)];
        s.x += v.x; s.y += v.y; s.z += v.z; s.w += v.w;
    }
    y[i] = s;
}

// ---------------------------------------------------------------------------
extern "C" void kernel_launch(void* const* d_in, const int* in_sizes, int n_in,
                              void* d_out, int out_size, void* d_ws, size_t ws_size,
                              hipStream_t stream) {
    const float* x      = (const float*)d_in[0];
    const float* eps    = (const float*)d_in[1];
    const float* loc    = (const float*)d_in[2];
    const float* logvar = (const float*)d_in[3];
    const float* cov    = (const float*)d_in[4];
    float* y = (float*)d_out;

    char* ws = (char*)d_ws;
    const size_t lb_bytes = (size_t)NPAD * KK * 2;            //  9.05 MB
    __hip_bfloat16* LB    = (__hip_bfloat16*)ws;
    float*          Ypart = (float*)(ws + lb_bytes);          // 17*MM*32*4 = 35.65 MB

    build_L_k<<<(NPAD * KK) / 256, 256, 0, stream>>>(cov, logvar, LB);
    gemm_v5_k<<<dim3(MM / BM, NBN), 256, 0, stream>>>(eps, LB, loc, x, Ypart);
    reduce_y_k<<<(MM * OUT_F / 4) / 256, 256, 0, stream>>>((const float4*)Ypart, (float4*)y);
}

// Round 5
// 356.998 us; speedup vs baseline: 2.5712x; 2.5712x over previous
//
#include <hip/hip_runtime.h>
#include <hip/hip_bf16.h>

// Problem constants (BayesianLinear): IN_F=64, OUT_F=32, N=2080, B*S=16384
#define IN_F  64
#define OUT_F 32
#define NV    2080           // N
#define NPAD  2176           // 17*128
#define MM    16384          // tokens
#define KK    2080           // contraction dim
#define NBN   17             // column tiles
#define BM    256            // row-tile

typedef __attribute__((ext_vector_type(4))) float f32x4;
typedef __bf16 bf16x8 __attribute__((ext_vector_type(8)));

using gas_ptr = const __attribute__((address_space(1))) void*;
using lds_ptr = __attribute__((address_space(3))) void*;

// ---------------------------------------------------------------------------
// Kernel 1: build L (bf16, row-major [NPAD][KK]); rows >= NV are zero.
// ---------------------------------------------------------------------------
__global__ __launch_bounds__(256) void build_L_k(const float* __restrict__ cov,
                                                 const float* __restrict__ logvar,
                                                 __hip_bfloat16* __restrict__ LB) {
    const int idx = blockIdx.x * 256 + threadIdx.x;   // over NPAD*KK
    const int m = idx / KK;
    const int k = idx - m * KK;
    float v = 0.0f;
    if (m < NV) {
        if (k < m)       v = cov[(size_t)(m * (m - 1) / 2) + k];
        else if (k == m) v = expf(0.5f * logvar[m]);
    }
    LB[idx] = __float2bfloat16(v);
}

// ---------------------------------------------------------------------------
// Kernel 2 (v6): v5 structure with the register-pressure fix.
//   A (eps fp32): direct global->reg per fragment (LDS trip provably
//     unnecessary: lane fragment = 8 contiguous fp32 at row*KK + quad*8).
//     ONE raw buffer ra[8] (32 VGPR) + ONE bf16 buffer af[4] (16 VGPR):
//     loads for t+1 issue pre-MFMA (MFMA block covers L2 latency); cvt
//     ra->af happens post-MFMA after vmcnt(2).  v5's raA/raB double buffer
//     (64 VGPR) caused accumulator spills (WRITE_SIZE 1.55 GB) -- removed.
//   B (L bf16): glds triple-buffer distance-2, counted vmcnt(2) keeps
//     B(t+2) in flight across the barrier; no lgkm drains, no ds_writes.
//   Per-iter LDS: 8 ds_read_b128 per wave (B frags only).
//   Triangular: kblocks=min(65,4bn+4); tail frag-skip jlo=2t-8bn.
// ---------------------------------------------------------------------------
__global__ __launch_bounds__(256, 2) void gemm_v6_k(const float* __restrict__ A,
                                                    const __hip_bfloat16* __restrict__ BT,
                                                    const float* __restrict__ loc,
                                                    const float* __restrict__ x,
                                                    float* __restrict__ Ypart) {
    __shared__ __align__(16) __hip_bfloat16 Bs[3][128 * 32];   // 24 KB
    __shared__ float xs[BM][4];                                //  4 KB

    const int tid  = threadIdx.x;
    const int bm   = blockIdx.x;             // 0..63
    const int bn   = (NBN - 1) - blockIdx.y; // heaviest (bn=16) first
    const int wave = tid >> 6;
    const int lane = tid & 63;
    const int quad = lane >> 4;
    const int r16  = lane & 15;
    const int kblocks = min(KK / 32, 4 * bn + 4);   // >= 4 always

    // xs: weight for h = 4bn-1+c; bias (1.0) at bn==0,c==0.
    {
        const int row = bm * BM + tid;
#pragma unroll
        for (int c = 0; c < 4; c++) {
            const int h = 4 * bn - 1 + c;
            float w = 0.0f;
            if (bn == 0 && c == 0)       w = 1.0f;
            else if (h >= 0 && h < IN_F) w = x[(size_t)row * IN_F + h];
            xs[tid][c] = w;
        }
    }

    const float*          __restrict__ Ag = A  + (size_t)bm * BM * KK;   // fp32 eps
    const __hip_bfloat16* __restrict__ Bg = BT + (size_t)bn * 128 * KK;  // bf16 L

    // A fragment global offsets (fp32 elements): lane frag i = 8 consecutive
    // f32 at row_i*KK + quad*8, row_i = 64*wave + 16*i + r16.
    size_t arofs[4];
#pragma unroll
    for (int i = 0; i < 4; i++) {
        const int row = 64 * wave + 16 * i + r16;
        arofs[i] = (size_t)row * KK + (size_t)(quad * 8);
    }

    // B staging map: 512 chunks, 2/thread; chunk c -> slot (c>>2, c&3) holding
    // global part p=(c&3)^((row>>1)&3)  (verified glds swizzle path).
    size_t bgofs[2]; int bldso[2];
#pragma unroll
    for (int u = 0; u < 2; u++) {
        const int c = tid + 256 * u;
        const int r = c >> 2, p = (c & 3) ^ ((r >> 1) & 3);
        bgofs[u] = (size_t)r * KK + (size_t)(p * 8);
        bldso[u] = c * 8;
    }

    // B fragment-read LDS offsets (elements), verified swizzle
    int bofs[8];
#pragma unroll
    for (int j = 0; j < 8; j++) {
        const int brow = 16 * j + r16;
        bofs[j] = brow * 32 + (quad ^ ((brow >> 1) & 3)) * 8;
    }

    f32x4 acc[4][8];
#pragma unroll
    for (int i = 0; i < 4; i++)
#pragma unroll
        for (int j = 0; j < 8; j++) acc[i][j] = f32x4{0.f, 0.f, 0.f, 0.f};

    f32x4  ra[8];   // single in-flight raw A K-tile (fp32)
    bf16x8 af[4];   // current A fragments (bf16)

    auto loadA = [&](int t) __attribute__((always_inline)) {
        const float* p = Ag + (size_t)t * 32;
#pragma unroll
        for (int i = 0; i < 4; i++) {
            ra[2 * i]     = *(const f32x4*)(p + arofs[i]);
            ra[2 * i + 1] = *(const f32x4*)(p + arofs[i] + 4);
        }
    };
    auto cvtA = [&]() __attribute__((always_inline)) {
#pragma unroll
        for (int i = 0; i < 4; i++) {
#pragma unroll
            for (int q = 0; q < 4; q++) {
                af[i][q]     = (__bf16)ra[2 * i][q];
                af[i][4 + q] = (__bf16)ra[2 * i + 1][q];
            }
        }
    };
    auto stageB = [&](int t, int buf) __attribute__((always_inline)) {
        const __hip_bfloat16* bp = Bg + (size_t)t * 32;
#pragma unroll
        for (int u = 0; u < 2; u++)
            __builtin_amdgcn_global_load_lds((gas_ptr)(bp + bgofs[u]),
                                             (lds_ptr)(&Bs[buf][0] + bldso[u]), 16, 0, 0);
    };

    // --- prologue: issue B(0), A(0), B(1); cvt A(0); barrier for xs+B(0) ---
    stageB(0, 0);
    loadA(0);
    stageB(1, 1);
    __builtin_amdgcn_sched_barrier(0);
    asm volatile("s_waitcnt vmcnt(2)" ::: "memory");     // B(0)+A(0) landed; B(1) in flight
    cvtA();
    asm volatile("s_waitcnt lgkmcnt(0)" ::: "memory");   // xs committed
    __builtin_amdgcn_s_barrier();
    __builtin_amdgcn_sched_barrier(0);

    // iter t entry invariant: af = A(t); Bs[t%3] ready; B(t+1)[2] in flight.
    // issue loadA(t+1)[8], stageB(t+2)[2]; MFMA; vmcnt(2) drains B(t+1)+A(t+1)
    // keeping B(t+2); cvt A(t+1); barrier.
    auto iter = [&](int t, int jlo) __attribute__((always_inline)) {
        const bool pfA = (t + 1 < kblocks);
        const bool pfB = (t + 2 < kblocks);
        if (pfA) loadA(t + 1);
        if (pfB) stageB(t + 2, (t + 2) % 3);
        __builtin_amdgcn_sched_barrier(0);

        const __hip_bfloat16* bs = &Bs[t % 3][0];
        __builtin_amdgcn_s_setprio(1);
#pragma unroll
        for (int j = 0; j < 8; j++) {
            if (j >= jlo) {
                const bf16x8 bfr = *(const bf16x8*)(bs + bofs[j]);
#pragma unroll
                for (int i = 0; i < 4; i++)
                    acc[i][j] = __builtin_amdgcn_mfma_f32_16x16x32_bf16(af[i], bfr, acc[i][j], 0, 0, 0);
            }
        }
        __builtin_amdgcn_s_setprio(0);

        if (pfA) {
            if (pfB) { asm volatile("s_waitcnt vmcnt(2)" ::: "memory"); }
            else     { asm volatile("s_waitcnt vmcnt(0)" ::: "memory"); }
            cvtA();                                   // af <- A(t+1)
            __builtin_amdgcn_s_barrier();
            __builtin_amdgcn_sched_barrier(0);
        }
    };

    const int t_full = min(kblocks, 4 * bn + 1);   // jlo==0 region
    int t = 0;
    for (; t < t_full; ++t) iter(t, 0);            // hot loop, branchless MFMAs
    for (; t < kblocks; ++t)                       // <=3 tail iters, jlo in {2,4,6}
        iter(t, 2 * t - 8 * bn);

    // in-lane epilogue.  C/D layout (m89): col=lane&15 (per 16-tile), row=quad*4+reg
    float locv[8];
#pragma unroll
    for (int j = 0; j < 8; j++) {
        const int col = bn * 128 + 16 * j + r16;
        locv[j] = (col < NV) ? loc[col] : 0.0f;
    }

    float* yp = Ypart + ((size_t)bn * MM + (size_t)bm * BM) * OUT_F;
#pragma unroll
    for (int i = 0; i < 4; i++) {
#pragma unroll
        for (int r = 0; r < 4; r++) {
            const int tl = 64 * wave + 16 * i + 4 * quad + r;
            float v0 = 0.0f, v1 = 0.0f;
#pragma unroll
            for (int c = 0; c < 4; c++) {
                const float w = xs[tl][c];
                v0 += w * (acc[i][2 * c][r]     + locv[2 * c]);
                v1 += w * (acc[i][2 * c + 1][r] + locv[2 * c + 1]);
            }
            yp[(size_t)tl * OUT_F + r16]      = v0;
            yp[(size_t)tl * OUT_F + 16 + r16] = v1;
        }
    }
}

// ---------------------------------------------------------------------------
// Kernel 3: reduce 17 partials -> y
// ---------------------------------------------------------------------------
__global__ __launch_bounds__(256) void reduce_y_k(const float4* __restrict__ yp,
                                                  float4* __restrict__ y) {
    const size_t i = (size_t)blockIdx.x * 256 + threadIdx.x;   // MM*32/4
    float4 s = yp[i];
#pragma unroll
    for (int b = 1; b < NBN; b++) {
        float4 v = yp[i + (size_t)b * (MM * OUT_F / 4)];
        s.x += v.x; s.y += v.y; s.z += v.z; s.w += v.w;
    }
    y[i] = s;
}

// ---------------------------------------------------------------------------
extern "C" void kernel_launch(void* const* d_in, const int* in_sizes, int n_in,
                              void* d_out, int out_size, void* d_ws, size_t ws_size,
                              hipStream_t stream) {
    const float* x      = (const float*)d_in[0];
    const float* eps    = (const float*)d_in[1];
    const float* loc    = (const float*)d_in[2];
    const float* logvar = (const float*)d_in[3];
    const float* cov    = (const float*)d_in[4];
    float* y = (float*)d_out;

    char* ws = (char*)d_ws;
    const size_t lb_bytes = (size_t)NPAD * KK * 2;            //  9.05 MB
    __hip_bfloat16* LB    = (__hip_bfloat16*)ws;
    float*          Ypart = (float*)(ws + lb_bytes);          // 17*MM*32*4 = 35.65 MB

    build_L_k<<<(NPAD * KK) / 256, 256, 0, stream>>>(cov, logvar, LB);
    gemm_v6_k<<<dim3(MM / BM, NBN), 256, 0, stream>>>(eps, LB, loc, x, Ypart);
    reduce_y_k<<<(MM * OUT_F / 4) / 256, 256, 0, stream>>>((const float4*)Ypart, (float4*)y);
}

// Round 6
// 323.063 us; speedup vs baseline: 2.8413x; 1.1050x over previous
//
#include <hip/hip_runtime.h>
#include <hip/hip_bf16.h>

// Problem constants (BayesianLinear): IN_F=64, OUT_F=32, N=2080, B*S=16384
#define IN_F  64
#define OUT_F 32
#define NV    2080           // N
#define MM    16384          // tokens
#define KK    2080           // contraction dim
#define NBN   17             // column tiles
#define NKT   65             // K tiles (KK/32)
#define BM    256            // row-tile

typedef __attribute__((ext_vector_type(4))) float f32x4;
typedef __bf16 bf16x8 __attribute__((ext_vector_type(8)));

using gas_ptr = const __attribute__((address_space(1))) void*;
using lds_ptr = __attribute__((address_space(3))) void*;

// ---------------------------------------------------------------------------
// Kernel 1: build L in FRAGMENT-LINEAR layout LB2.
// Chunk index idx = ((bn*65 + t)*8 + j)*64 + lane; chunk = 8 bf16 =
//   L[row = bn*128 + 16j + (lane&15)][k = t*32 + (lane>>4)*8 .. +8]
// (zeros for k>row, row>=NV).  A wave's B-frag load in the gemm is then ONE
// contiguous-1KB global_load_dwordx4 -- no LDS staging for B at all.
// ---------------------------------------------------------------------------
__global__ __launch_bounds__(256) void build_L2_k(const float* __restrict__ cov,
                                                  const float* __restrict__ logvar,
                                                  __hip_bfloat16* __restrict__ LB2) {
    const int idx  = blockIdx.x * 256 + threadIdx.x;   // [0, 17*65*8*64)
    const int lane = idx & 63;
    const int j    = (idx >> 6) & 7;
    const int rem  = idx >> 9;          // bn*65 + t
    const int t    = rem % NKT;
    const int bn   = rem / NKT;
    const int row  = bn * 128 + 16 * j + (lane & 15);
    const int k0   = t * 32 + (lane >> 4) * 8;

    bf16x8 w;
#pragma unroll
    for (int e = 0; e < 8; e++) {
        const int k = k0 + e;
        float v = 0.0f;
        if (row < NV) {
            if (k < row)       v = cov[(size_t)(row * (row - 1) / 2) + k];
            else if (k == row) v = expf(0.5f * logvar[row]);
        }
        w[e] = (__bf16)v;
    }
    *(bf16x8*)(LB2 + (size_t)idx * 8) = w;
}

// ---------------------------------------------------------------------------
// Kernel 2 (v7): BM=256 x 128 tile, acc[4][8] per wave (4 waves).
//   A (eps fp32): global_load_lds DIRECT as fp32 (coalesced 16B/lane chunks;
//     v6 showed per-lane fragment loads from global shatter into ~16
//     transactions/instr).  Chunk swizzle o=(c&7)^(r&7) makes the fragment
//     ds_read_b128s bank-uniform.  In-reg fp32->bf16 cvt after LDS read.
//     No eps pre-pass kernel needed.
//   B (L bf16): NO LDS -- direct per-lane dwordx4 from the fragment-linear
//     LB2 (L2-hot 0.53 MB strip shared by all 64 bm-blocks).
//   Per-iter, per-wave: 8 A-glds, 8 A ds_read_b128, 8 B dwordx4, 32 MFMA,
//     ONE barrier, counted vmcnt(8) only (A-glds drained, next B kept in
//     flight across the barrier; B's MFMA wait is auto vmcnt(8) keeping the
//     A-glds in flight).  No lgkm drains in the loop, no ds_writes.
//   Triangular: kblocks=min(65,4bn+4); tail MFMA frag-skip jlo=2t-8bn.
// ---------------------------------------------------------------------------
__global__ __launch_bounds__(256, 2) void gemm_v7_k(const float* __restrict__ A,
                                                    const __hip_bfloat16* __restrict__ BT2,
                                                    const float* __restrict__ loc,
                                                    const float* __restrict__ x,
                                                    float* __restrict__ Ypart) {
    __shared__ __align__(16) float As[2][BM * 32];   // 2 x 32 KB (fp32 K-tiles)
    __shared__ float xs[BM][4];                      // 4 KB

    const int tid  = threadIdx.x;
    const int bm   = blockIdx.x;             // 0..63
    const int bn   = (NBN - 1) - blockIdx.y; // heaviest (bn=16) first
    const int wave = tid >> 6;
    const int lane = tid & 63;
    const int quad = lane >> 4;
    const int r16  = lane & 15;
    const int kblocks = min(NKT, 4 * bn + 4);   // >= 4 always

    // xs: weight for h = 4bn-1+c; bias (1.0) at bn==0,c==0.
    {
        const int row = bm * BM + tid;
#pragma unroll
        for (int c = 0; c < 4; c++) {
            const int h = 4 * bn - 1 + c;
            float w = 0.0f;
            if (bn == 0 && c == 0)       w = 1.0f;
            else if (h >= 0 && h < IN_F) w = x[(size_t)row * IN_F + h];
            xs[tid][c] = w;
        }
    }

    const float* __restrict__ Ag = A + (size_t)bm * BM * KK;            // fp32 eps
    const __hip_bfloat16* __restrict__ Bg2 =
        BT2 + (size_t)bn * NKT * 4096;                                  // frag-linear L

    // A staging map: 2048 chunks of 16B (4 fp32), 8/thread.
    // chunk c -> (row r=c>>3, oct o=(c&7)^(r&7)); src = r*KK + t*32 + o*4.
    size_t sofs[8]; int dofs[8];
#pragma unroll
    for (int u = 0; u < 8; u++) {
        const int c = tid + 256 * u;
        const int r = c >> 3, o = (c & 7) ^ (r & 7);
        sofs[u] = (size_t)r * KK + (size_t)(o * 4);
        dofs[u] = c * 4;                               // float offset in As
    }

    // A fragment-read LDS offsets (floats): frag i, lane (quad,r16):
    // row = 64w+16i+r16; octs {2q, 2q+1} -> chunks row*8 + (oct ^ (row&7)).
    int aof0[4], aof1[4];
#pragma unroll
    for (int i = 0; i < 4; i++) {
        const int row = 64 * wave + 16 * i + r16;
        aof0[i] = (row * 8 + ((2 * quad)     ^ (row & 7))) * 4;
        aof1[i] = (row * 8 + ((2 * quad + 1) ^ (row & 7))) * 4;
    }

    f32x4 acc[4][8];
#pragma unroll
    for (int i = 0; i < 4; i++)
#pragma unroll
        for (int j = 0; j < 8; j++) acc[i][j] = f32x4{0.f, 0.f, 0.f, 0.f};

    bf16x8 bcur[8];   // current B fragments (single-buffered, loaded distance-1)

    auto stageA = [&](int t, int buf) __attribute__((always_inline)) {
        const float* p = Ag + (size_t)t * 32;
#pragma unroll
        for (int u = 0; u < 8; u++)
            __builtin_amdgcn_global_load_lds((gas_ptr)(p + sofs[u]),
                                             (lds_ptr)(&As[buf][0] + dofs[u]), 16, 0, 0);
    };
    auto loadB = [&](int t) __attribute__((always_inline)) {
        const __hip_bfloat16* p = Bg2 + (size_t)t * 4096 + lane * 8;
#pragma unroll
        for (int j = 0; j < 8; j++)
            bcur[j] = *(const bf16x8*)(p + j * 512);
    };

    // --- prologue: A(0) glds, then B(0) regs; drain A(0) only ---
    stageA(0, 0);
    loadB(0);
    __builtin_amdgcn_sched_barrier(0);
    asm volatile("s_waitcnt vmcnt(8)" ::: "memory");     // A(0) landed; B(0) in flight
    asm volatile("s_waitcnt lgkmcnt(0)" ::: "memory");   // xs committed
    __builtin_amdgcn_s_barrier();
    __builtin_amdgcn_sched_barrier(0);

    // iter t invariant: As[t&1] ready (all waves); bcur = B(t) in flight
    // (own-wave loads, consumed via compiler auto vmcnt(8) which keeps the
    // A(t+1) glds flying).  End of iter: loadB(t+1); vmcnt(8) drains A(t+1)
    // glds and keeps B(t+1) in flight across the barrier.
    auto iter = [&](int t, int jlo) __attribute__((always_inline)) {
        const bool pf = (t + 1 < kblocks);
        if (pf) stageA(t + 1, (t + 1) & 1);
        __builtin_amdgcn_sched_barrier(0);

        const float* as = &As[t & 1][0];
        bf16x8 af[4];
#pragma unroll
        for (int i = 0; i < 4; i++) {
            const f32x4 x0 = *(const f32x4*)(as + aof0[i]);
            const f32x4 x1 = *(const f32x4*)(as + aof1[i]);
#pragma unroll
            for (int q = 0; q < 4; q++) {
                af[i][q]     = (__bf16)x0[q];
                af[i][4 + q] = (__bf16)x1[q];
            }
        }
#pragma unroll
        for (int j = 0; j < 8; j++) {
            if (j >= jlo) {
#pragma unroll
                for (int i = 0; i < 4; i++)
                    acc[i][j] = __builtin_amdgcn_mfma_f32_16x16x32_bf16(af[i], bcur[j], acc[i][j], 0, 0, 0);
            }
        }

        if (pf) {
            loadB(t + 1);                                    // overwrites bcur (consumed)
            asm volatile("s_waitcnt vmcnt(8)" ::: "memory"); // A(t+1) done; keep B(t+1)
            __builtin_amdgcn_s_barrier();
            __builtin_amdgcn_sched_barrier(0);
        }
    };

    const int t_full = min(kblocks, 4 * bn + 1);   // jlo==0 region
    int t = 0;
    for (; t < t_full; ++t) iter(t, 0);            // hot loop, branchless MFMAs
    for (; t < kblocks; ++t)                       // <=3 tail iters, jlo in {2,4,6}
        iter(t, 2 * t - 8 * bn);

    // in-lane epilogue.  C/D layout (m89): col=lane&15 (per 16-tile), row=quad*4+reg
    float locv[8];
#pragma unroll
    for (int j = 0; j < 8; j++) {
        const int col = bn * 128 + 16 * j + r16;
        locv[j] = (col < NV) ? loc[col] : 0.0f;
    }

    float* yp = Ypart + ((size_t)bn * MM + (size_t)bm * BM) * OUT_F;
#pragma unroll
    for (int i = 0; i < 4; i++) {
#pragma unroll
        for (int r = 0; r < 4; r++) {
            const int tl = 64 * wave + 16 * i + 4 * quad + r;
            float v0 = 0.0f, v1 = 0.0f;
#pragma unroll
            for (int c = 0; c < 4; c++) {
                const float w = xs[tl][c];
                v0 += w * (acc[i][2 * c][r]     + locv[2 * c]);
                v1 += w * (acc[i][2 * c + 1][r] + locv[2 * c + 1]);
            }
            yp[(size_t)tl * OUT_F + r16]      = v0;
            yp[(size_t)tl * OUT_F + 16 + r16] = v1;
        }
    }
}

// ---------------------------------------------------------------------------
// Kernel 3: reduce 17 partials -> y
// ---------------------------------------------------------------------------
__global__ __launch_bounds__(256) void reduce_y_k(const float4* __restrict__ yp,
                                                  float4* __restrict__ y) {
    const size_t i = (size_t)blockIdx.x * 256 + threadIdx.x;   // MM*32/4
    float4 s = yp[i];
#pragma unroll
    for (int b = 1; b < NBN; b++) {
        float4 v = yp[i + (size_t)b * (MM * OUT_F / 4)];
        s.x += v.x; s.y += v.y; s.z += v.z; s.w += v.w;
    }
    y[i] = s;
}

// ---------------------------------------------------------------------------
extern "C" void kernel_launch(void* const* d_in, const int* in_sizes, int n_in,
                              void* d_out, int out_size, void* d_ws, size_t ws_size,
                              hipStream_t stream) {
    const float* x      = (const float*)d_in[0];
    const float* eps    = (const float*)d_in[1];
    const float* loc    = (const float*)d_in[2];
    const float* logvar = (const float*)d_in[3];
    const float* cov    = (const float*)d_in[4];
    float* y = (float*)d_out;

    char* ws = (char*)d_ws;
    const size_t lb2_bytes = (size_t)NBN * NKT * 4096 * 2;    // 8.84 MB
    __hip_bfloat16* LB2   = (__hip_bfloat16*)ws;
    float*          Ypart = (float*)(ws + lb2_bytes);         // 17*MM*32*4 = 35.65 MB

    build_L2_k<<<(NBN * NKT * 8 * 64) / 256, 256, 0, stream>>>(cov, logvar, LB2);
    gemm_v7_k<<<dim3(MM / BM, NBN), 256, 0, stream>>>(eps, LB2, loc, x, Ypart);
    reduce_y_k<<<(MM * OUT_F / 4) / 256, 256, 0, stream>>>((const float4*)Ypart, (float4*)y);
}